// Round 1
// baseline (391.775 us; speedup 1.0000x reference)
//
#include <hip/hip_runtime.h>
#include <hip/hip_bf16.h>
#include <math.h>

#define H    128
#define NB   4      // batch
#define NSEG 200    // segments
#define NS   512    // tokens per segment

// ---------------------------------------------------------------------------
// ws layout (floats):
//   v    : [0,    512)                       q @ Wc  per batch
//   c0   : [512,  516)                       q . bc  per batch
//   w    : [1024, 1024+B*N*S)                softmax weights (409,600 floats)
//   part : [410624, 410624 + 4*B*S*H)        token_result n-split partials
// ---------------------------------------------------------------------------

// Kernel 1: fold both linear projections into a per-batch vector.
// q[b,h] = query[b,:] . Wq[h,:] + bq[h]
// v[b,k] = sum_h q[b,h] * Wc[h,k]     (so att = context . v + c0)
// c0[b]  = sum_h q[b,h] * bc[h]
__global__ void precompute_kernel(const float* __restrict__ query,
                                  const float* __restrict__ Wq,
                                  const float* __restrict__ bq,
                                  const float* __restrict__ Wc,
                                  const float* __restrict__ bc,
                                  float* __restrict__ v_out,
                                  float* __restrict__ c0_out) {
    __shared__ float qsh[H];
    __shared__ float red[H];
    const int tid = threadIdx.x;   // 0..127
    for (int b = 0; b < NB; ++b) {
        float acc = bq[tid];
        const float* qr = query + b * H;
        const float* wr = Wq + tid * H;
        for (int k = 0; k < H; ++k) acc += qr[k] * wr[k];
        qsh[tid] = acc;
        __syncthreads();
        float vacc = 0.f;
        for (int h2 = 0; h2 < H; ++h2) vacc += qsh[h2] * Wc[h2 * H + tid];
        v_out[b * H + tid] = vacc;
        red[tid] = qsh[tid] * bc[tid];
        __syncthreads();
        for (int off = H / 2; off > 0; off >>= 1) {
            if (tid < off) red[tid] += red[tid + off];
            __syncthreads();
        }
        if (tid == 0) c0_out[b] = red[0];
        __syncthreads();
    }
}

// Kernel 2 (fused): per (b,n) segment — scores, mask, softmax, and the
// over-S weighted reduction result[b,n,:]. One block per segment.
__global__ __launch_bounds__(512)
void att_softmax_result_kernel(const float* __restrict__ context,
                               const float* __restrict__ mask,
                               const float* __restrict__ v,
                               const float* __restrict__ c0,
                               float* __restrict__ w_out,
                               float* __restrict__ result_out) {
    __shared__ float  vv[H];
    __shared__ float  sc[NS];
    __shared__ float  red[NS];
    __shared__ float4 red4[16 * 32];

    const int tid = threadIdx.x;           // 0..511
    const int blk = blockIdx.x;            // b*NSEG + n
    const int b   = blk / NSEG;
    const float* ctx = context + (size_t)blk * NS * H;

    if (tid < H) vv[tid] = v[b * H + tid];
    const float c0b = c0[b];
    __syncthreads();

    // ---- phase 1: att[s] = ctx[s,:] . v + c0, times mask ----
    {
        const int s = tid;
        const float4* crow = (const float4*)(ctx + (size_t)s * H);
        float acc = c0b;
        #pragma unroll
        for (int k = 0; k < H / 4; ++k) {
            float4 cv = crow[k];
            acc += cv.x * vv[4 * k + 0] + cv.y * vv[4 * k + 1]
                 + cv.z * vv[4 * k + 2] + cv.w * vv[4 * k + 3];
        }
        acc *= mask[(size_t)blk * NS + s];
        sc[s]  = acc;
        red[s] = acc;
    }
    __syncthreads();

    // ---- phase 2: softmax over 512 tokens ----
    for (int off = NS / 2; off > 0; off >>= 1) {
        if (tid < off) red[tid] = fmaxf(red[tid], red[tid + off]);
        __syncthreads();
    }
    const float mx = red[0];
    __syncthreads();
    const float e = __expf(sc[tid] - mx);
    sc[tid]  = e;
    red[tid] = e;
    __syncthreads();
    for (int off = NS / 2; off > 0; off >>= 1) {
        if (tid < off) red[tid] += red[tid + off];
        __syncthreads();
    }
    const float inv = 1.0f / red[0];
    const float wv  = e * inv;
    sc[tid] = wv;
    w_out[(size_t)blk * NS + tid] = wv;
    __syncthreads();

    // ---- phase 3: result[b,n,h] = sum_s w[s] * ctx[s,h] (segment is L1/L2-hot) ----
    {
        const int h4 = tid & 31;       // float4 chunk over H
        const int g  = tid >> 5;       // 0..15 s-subgroup
        float4 acc = {0.f, 0.f, 0.f, 0.f};
        const float4* c4 = (const float4*)ctx;
        for (int s = g; s < NS; s += 16) {
            const float ws_ = sc[s];
            float4 cv = c4[(size_t)s * 32 + h4];
            acc.x += ws_ * cv.x; acc.y += ws_ * cv.y;
            acc.z += ws_ * cv.z; acc.w += ws_ * cv.w;
        }
        red4[g * 32 + h4] = acc;
        __syncthreads();
        for (int off = 8; off > 0; off >>= 1) {
            if (g < off) {
                float4 o = red4[(g + off) * 32 + h4];
                float4 m = red4[g * 32 + h4];
                m.x += o.x; m.y += o.y; m.z += o.z; m.w += o.w;
                red4[g * 32 + h4] = m;
            }
            __syncthreads();
        }
        if (g == 0)
            ((float4*)result_out)[(size_t)blk * 32 + h4] = red4[h4];
    }
}

// Kernel 3: token_result[b,s,h] = sum_n w[b,n,s] * ctx[b,n,s,h].
// N-split across blocks (partials) for extra latency-hiding parallelism.
__global__ __launch_bounds__(256)
void token_partial_kernel(const float* __restrict__ context,
                          const float* __restrict__ w,
                          float* __restrict__ out,
                          int nsplit) {
    const int tiles = NB * NS / 8;
    const int tile  = blockIdx.x % tiles;
    const int split = blockIdx.x / tiles;
    const int n_per = NSEG / nsplit;
    const int n0 = split * n_per, n1 = n0 + n_per;

    const int tid = threadIdx.x;
    const int h4  = tid & 31;            // float4 chunk over H
    const int j   = tid >> 5;            // 0..7
    const int b   = tile / (NS / 8);
    const int s   = (tile % (NS / 8)) * 8 + j;

    float4 acc = {0.f, 0.f, 0.f, 0.f};
    #pragma unroll 4
    for (int n = n0; n < n1; ++n) {
        const size_t row = (size_t)(b * NSEG + n) * NS + s;
        const float wv = w[row];
        float4 cv = ((const float4*)context)[row * 32 + h4];
        acc.x += wv * cv.x; acc.y += wv * cv.y;
        acc.z += wv * cv.z; acc.w += wv * cv.w;
    }
    ((float4*)out)[(size_t)split * (NB * NS * H / 4)
                   + ((size_t)b * NS + s) * 32 + h4] = acc;
}

// Kernel 4: sum the nsplit partials into the token_result output section.
__global__ void combine_kernel(const float* __restrict__ part,
                               float* __restrict__ out, int nsplit) {
    const int i = blockIdx.x * blockDim.x + threadIdx.x;  // float4 index
    const float4* p = (const float4*)part;
    float4 acc = p[i];
    for (int sp = 1; sp < nsplit; ++sp) {
        float4 o = p[(size_t)sp * (NB * NS * H / 4) + i];
        acc.x += o.x; acc.y += o.y; acc.z += o.z; acc.w += o.w;
    }
    ((float4*)out)[i] = acc;
}

extern "C" void kernel_launch(void* const* d_in, const int* in_sizes, int n_in,
                              void* d_out, int out_size, void* d_ws, size_t ws_size,
                              hipStream_t stream) {
    const float* query   = (const float*)d_in[0];
    const float* context = (const float*)d_in[1];
    const float* mask    = (const float*)d_in[2];
    const float* Wq      = (const float*)d_in[3];
    const float* bq      = (const float*)d_in[4];
    const float* Wc      = (const float*)d_in[5];
    const float* bc      = (const float*)d_in[6];

    float* out = (float*)d_out;
    float* wsf = (float*)d_ws;

    float* v    = wsf;                          // 512
    float* c0   = wsf + 512;                    // 4
    float* w    = wsf + 1024;                   // B*N*S = 409600
    float* part = wsf + 1024 + NB * NSEG * NS;  // 4 * B*S*H = 1,048,576

    float* result_out = out;                    // [B,N,H] = 102,400 floats
    float* token_out  = out + NB * NSEG * H;    // [B,S,H] = 262,144 floats

    const size_t need_split = (size_t)(1024 + NB * NSEG * NS + 4 * NB * NS * H) * sizeof(float);
    const int nsplit = (ws_size >= need_split) ? 4 : 1;

    precompute_kernel<<<1, 128, 0, stream>>>(query, Wq, bq, Wc, bc, v, c0);
    att_softmax_result_kernel<<<NB * NSEG, 512, 0, stream>>>(
        context, mask, v, c0, w, result_out);
    if (nsplit == 4) {
        token_partial_kernel<<<4 * NB * NS / 8, 256, 0, stream>>>(context, w, part, 4);
        combine_kernel<<<NB * NS * H / 4 / 256, 256, 0, stream>>>(part, token_out, 4);
    } else {
        token_partial_kernel<<<NB * NS / 8, 256, 0, stream>>>(context, w, token_out, 1);
    }
}

// Round 2
// 353.757 us; speedup vs baseline: 1.1075x; 1.1075x over previous
//
#include <hip/hip_runtime.h>
#include <hip/hip_bf16.h>
#include <math.h>

#define H    128
#define NB   4      // batch
#define NSEG 200    // segments
#define NS   512    // tokens per segment
#define GN   10     // n-rows per weighted-kernel block
#define GS   64     // s-rows per weighted-kernel block
#define NGRP (NSEG / GN)   // 20
#define NST  (NS / GS)     // 8

// ---------------------------------------------------------------------------
// ws layout (floats):
//   v           : [0, 512)
//   c0          : [512, 516)
//   w           : [1024, 410624)                    B*N*S softmax weights
//   result_part : [410624, 1229824)                 B*N*NST*H
//   token_part  : [1229824, 6472704)                NGRP*B*S*H
// ---------------------------------------------------------------------------

// Fold both projections into per-batch vector: att = ctx . v + c0
__global__ void precompute_kernel(const float* __restrict__ query,
                                  const float* __restrict__ Wq,
                                  const float* __restrict__ bq,
                                  const float* __restrict__ Wc,
                                  const float* __restrict__ bc,
                                  float* __restrict__ v_out,
                                  float* __restrict__ c0_out) {
    __shared__ float qsh[H];
    __shared__ float red[H];
    const int tid = threadIdx.x;      // 0..127
    const int b   = blockIdx.x;       // 0..3
    float acc = bq[tid];
    const float* qr = query + b * H;
    const float* wr = Wq + tid * H;
    for (int k = 0; k < H; ++k) acc += qr[k] * wr[k];
    qsh[tid] = acc;
    __syncthreads();
    float vacc = 0.f;
    for (int h2 = 0; h2 < H; ++h2) vacc += qsh[h2] * Wc[h2 * H + tid];
    v_out[b * H + tid] = vacc;
    red[tid] = qsh[tid] * bc[tid];
    __syncthreads();
    for (int off = H / 2; off > 0; off >>= 1) {
        if (tid < off) red[tid] += red[tid + off];
        __syncthreads();
    }
    if (tid == 0) c0_out[b] = red[0];
}

// Pass A: per-(b,n) segment — coalesced dot-scores, mask, softmax, write w.
__global__ __launch_bounds__(512)
void scores_softmax_kernel(const float* __restrict__ context,
                           const float* __restrict__ mask,
                           const float* __restrict__ v,
                           const float* __restrict__ c0,
                           float* __restrict__ w_out) {
    __shared__ float4 vv4[32];
    __shared__ float  mk[NS];
    __shared__ float  sc[NS];
    __shared__ float  wred[8];

    const int tid = threadIdx.x;       // 0..511
    const int blk = blockIdx.x;        // b*NSEG + n
    const int b   = blk / NSEG;
    const float* cseg = context + (size_t)blk * NS * H;

    if (tid < 32) vv4[tid] = ((const float4*)(v + b * H))[tid];
    mk[tid] = mask[(size_t)blk * NS + tid];
    __syncthreads();

    const int   h4  = tid & 31;        // float4 chunk within row
    const int   rg  = tid >> 5;        // 0..15 rows in flight
    const float c0b = c0[b];

    // 32 lanes per row: wave load = 1 KB contiguous (2 adjacent rows)
    #pragma unroll 4
    for (int it = 0; it < NS / 16; ++it) {
        const int s = it * 16 + rg;
        const float4 cv = ((const float4*)(cseg + (size_t)s * H))[h4];
        const float4 vq = vv4[h4];
        float p = cv.x * vq.x + cv.y * vq.y + cv.z * vq.z + cv.w * vq.w;
        p += __shfl_xor(p, 16);
        p += __shfl_xor(p, 8);
        p += __shfl_xor(p, 4);
        p += __shfl_xor(p, 2);
        p += __shfl_xor(p, 1);
        if (h4 == 0) sc[s] = (p + c0b) * mk[s];
    }
    __syncthreads();

    // softmax over 512 elements, one per thread
    const float x = sc[tid];
    float m = x;
    for (int o = 32; o > 0; o >>= 1) m = fmaxf(m, __shfl_xor(m, o));
    const int wid = tid >> 6, lane = tid & 63;
    if (lane == 0) wred[wid] = m;
    __syncthreads();
    if (tid == 0) {
        float mm = wred[0];
        for (int i = 1; i < 8; ++i) mm = fmaxf(mm, wred[i]);
        wred[0] = mm;
    }
    __syncthreads();
    const float mx = wred[0];
    const float e  = __expf(x - mx);
    float ssum = e;
    for (int o = 32; o > 0; o >>= 1) ssum += __shfl_xor(ssum, o);
    __syncthreads();                     // all reads of wred[0] done
    if (lane == 0) wred[wid] = ssum;
    __syncthreads();
    if (tid == 0) {
        float t = 0.f;
        for (int i = 0; i < 8; ++i) t += wred[i];
        wred[0] = t;
    }
    __syncthreads();
    w_out[(size_t)blk * NS + tid] = e / wred[0];
}

// Pass C: ONE coalesced read of context -> partials for BOTH outputs.
// Block owns (b, 10 n-rows, 64 s-rows). token partial in registers
// (conflict-free: thread owns (s,h4)); result partial in registers per n,
// reduced over the 16 s-subgroups via batched LDS trees at block end.
__global__ __launch_bounds__(512)
void weighted_kernel(const float* __restrict__ context,
                     const float* __restrict__ w,
                     float* __restrict__ result_part,
                     float* __restrict__ token_part) {
    const int bid = blockIdx.x;            // ((b*NGRP + ng)*NST + st)
    const int st  = bid & (NST - 1);
    const int tmp = bid / NST;
    const int ng  = tmp % NGRP;
    const int b   = tmp / NGRP;
    const int n0  = ng * GN;
    const int s0  = st * GS;

    const int tid = threadIdx.x;
    const int h4  = tid & 31;              // float4 chunk within row
    const int rg  = tid >> 5;              // 0..15 s-subgroup

    __shared__ float  wt[GN * GS];         // 2.5 KB
    __shared__ float4 red4[5 * 16 * 32];   // 40 KB

    for (int i = tid; i < GN * GS; i += 512) {
        const int nn = i >> 6, ss = i & (GS - 1);
        wt[i] = w[((size_t)(b * NSEG + n0 + nn)) * NS + s0 + ss];
    }
    __syncthreads();

    float4 racc[GN];
    float4 tacc[4];
    #pragma unroll
    for (int n = 0; n < GN; ++n) racc[n] = make_float4(0.f, 0.f, 0.f, 0.f);
    #pragma unroll
    for (int j = 0; j < 4; ++j) tacc[j] = make_float4(0.f, 0.f, 0.f, 0.f);

    #pragma unroll
    for (int n = 0; n < GN; ++n) {
        const float* base = context + ((size_t)(b * NSEG + n0 + n) * NS + s0) * (size_t)H;
        #pragma unroll
        for (int j = 0; j < 4; ++j) {
            const int s = j * 16 + rg;
            const float  wv = wt[n * GS + s];
            const float4 cv = ((const float4*)(base + (size_t)s * H))[h4];
            racc[n].x += wv * cv.x; racc[n].y += wv * cv.y;
            racc[n].z += wv * cv.z; racc[n].w += wv * cv.w;
            tacc[j].x += wv * cv.x; tacc[j].y += wv * cv.y;
            tacc[j].z += wv * cv.z; tacc[j].w += wv * cv.w;
        }
    }

    // token partial: [ng][b][s][h], fully written by this block's (s,h4) owners
    #pragma unroll
    for (int j = 0; j < 4; ++j) {
        const int s = j * 16 + rg;
        ((float4*)token_part)[(((size_t)ng * NB + b) * NS + s0 + s) * 32 + h4] = tacc[j];
    }

    // result partial: reduce racc over 16 rg-groups, batched 5 n per tree round
    for (int nb = 0; nb < GN; nb += 5) {
        #pragma unroll
        for (int j = 0; j < 5; ++j)
            red4[(j * 16 + rg) * 32 + h4] = racc[nb + j];
        __syncthreads();
        for (int off = 8; off > 0; off >>= 1) {
            if (rg < off) {
                #pragma unroll
                for (int j = 0; j < 5; ++j) {
                    float4 o = red4[(j * 16 + rg + off) * 32 + h4];
                    float4 mm = red4[(j * 16 + rg) * 32 + h4];
                    mm.x += o.x; mm.y += o.y; mm.z += o.z; mm.w += o.w;
                    red4[(j * 16 + rg) * 32 + h4] = mm;
                }
            }
            __syncthreads();
        }
        if (rg == 0) {
            #pragma unroll
            for (int j = 0; j < 5; ++j)
                ((float4*)result_part)[(((size_t)(b * NSEG + n0 + nb + j)) * NST + st) * 32 + h4]
                    = red4[(j * 16) * 32 + h4];
        }
        __syncthreads();
    }
}

// result[b,n,h] = sum over NST s-tiles
__global__ void combine_result_kernel(const float* __restrict__ part,
                                      float* __restrict__ out) {
    const int i = blockIdx.x * blockDim.x + threadIdx.x;   // float4 over B*N*H/4
    const int row = i >> 5, h4 = i & 31;
    float4 acc = {0.f, 0.f, 0.f, 0.f};
    const float4* p = (const float4*)part;
    #pragma unroll
    for (int st = 0; st < NST; ++st) {
        float4 o = p[((size_t)row * NST + st) * 32 + h4];
        acc.x += o.x; acc.y += o.y; acc.z += o.z; acc.w += o.w;
    }
    ((float4*)out)[i] = acc;
}

// token_result[b,s,h] = sum over NGRP n-groups
__global__ void combine_token_kernel(const float* __restrict__ part,
                                     float* __restrict__ out) {
    const int i = blockIdx.x * blockDim.x + threadIdx.x;   // float4 over B*S*H/4
    float4 acc = {0.f, 0.f, 0.f, 0.f};
    const float4* p = (const float4*)part;
    #pragma unroll
    for (int g = 0; g < NGRP; ++g) {
        float4 o = p[(size_t)g * (NB * NS * H / 4) + i];
        acc.x += o.x; acc.y += o.y; acc.z += o.z; acc.w += o.w;
    }
    ((float4*)out)[i] = acc;
}

extern "C" void kernel_launch(void* const* d_in, const int* in_sizes, int n_in,
                              void* d_out, int out_size, void* d_ws, size_t ws_size,
                              hipStream_t stream) {
    const float* query   = (const float*)d_in[0];
    const float* context = (const float*)d_in[1];
    const float* mask    = (const float*)d_in[2];
    const float* Wq      = (const float*)d_in[3];
    const float* bq      = (const float*)d_in[4];
    const float* Wc      = (const float*)d_in[5];
    const float* bc      = (const float*)d_in[6];

    float* out = (float*)d_out;
    float* wsf = (float*)d_ws;

    float* v     = wsf;                                   // 512
    float* c0    = wsf + 512;                             // 4
    float* w     = wsf + 1024;                            // B*N*S
    float* rpart = wsf + 1024 + NB * NSEG * NS;           // B*N*NST*H
    float* tpart = rpart + NB * NSEG * NST * H;           // NGRP*B*S*H

    float* result_out = out;                              // [B,N,H]
    float* token_out  = out + NB * NSEG * H;              // [B,S,H]

    precompute_kernel<<<NB, 128, 0, stream>>>(query, Wq, bq, Wc, bc, v, c0);
    scores_softmax_kernel<<<NB * NSEG, 512, 0, stream>>>(context, mask, v, c0, w);
    weighted_kernel<<<NB * NGRP * NST, 512, 0, stream>>>(context, w, rpart, tpart);
    combine_result_kernel<<<NB * NSEG * H / 4 / 256, 256, 0, stream>>>(rpart, result_out);
    combine_token_kernel<<<NB * NS * H / 4 / 256, 256, 0, stream>>>(tpart, token_out);
}